// Round 1
// baseline (970.483 us; speedup 1.0000x reference)
//
#include <hip/hip_runtime.h>
#include <hip/hip_bf16.h>

#define NN 50000
#define NE 800000
#define NAF 9
#define NBF 3
#define BN_EPS 1e-5f

__device__ __forceinline__ float bcastf(float v, int k) {
  return __int_as_float(__builtin_amdgcn_readlane(__float_as_int(v), k));
}

// ---------------- K0: atom encoder (sum of 9 embedding rows) ----------------
__global__ __launch_bounds__(256) void k_atom(const int* __restrict__ x,
                                              const float* __restrict__ aemb,
                                              float* __restrict__ h) {
  int node = (blockIdx.x * 256 + threadIdx.x) >> 6;
  int lane = threadIdx.x & 63;
  if (node >= NN) return;
  const int* xr = x + node * NAF;
  float acc = 0.f;
#pragma unroll
  for (int f = 0; f < NAF; ++f) {
    acc += aemb[(f * 64 + xr[f]) * 64 + lane];
  }
  h[(size_t)node * 64 + lane] = acc;
}

// ---------------- CSR build ----------------
__global__ __launch_bounds__(256) void k_hist(const int* __restrict__ ei,
                                              int* __restrict__ counts) {
  int e = blockIdx.x * 256 + threadIdx.x;
  if (e < NE) atomicAdd(&counts[ei[NE + e]], 1);
}

__global__ __launch_bounds__(1024) void k_scan(const int* __restrict__ counts,
                                               int* __restrict__ row_ptr,
                                               int* __restrict__ fill) {
  const int SEG = (NN + 1023) / 1024;  // 49
  int tid = threadIdx.x;
  int lane = tid & 63, wid = tid >> 6;
  int start = tid * SEG;
  int end = start + SEG;
  if (end > NN) end = NN;
  if (start > NN) start = NN;
  int s = 0;
  for (int i = start; i < end; ++i) s += counts[i];
  int inc = s;
#pragma unroll
  for (int off = 1; off < 64; off <<= 1) {
    int t = __shfl_up(inc, off);
    if (lane >= off) inc += t;
  }
  __shared__ int wtot[16];
  if (lane == 63) wtot[wid] = inc;
  __syncthreads();
  if (tid == 0) {
    int run = 0;
    for (int w = 0; w < 16; ++w) { int t = wtot[w]; wtot[w] = run; run += t; }
  }
  __syncthreads();
  int exc = inc - s + wtot[wid];  // global exclusive prefix
  int run = exc;
  for (int i = start; i < end; ++i) {
    row_ptr[i] = run; fill[i] = run; run += counts[i];
  }
  if (tid == 1023) row_ptr[NN] = run;  // == NE
}

__global__ __launch_bounds__(256) void k_scatter(const int* __restrict__ ei,
                                                 const int* __restrict__ ea,
                                                 int* __restrict__ fill,
                                                 unsigned* __restrict__ epack) {
  int e = blockIdx.x * 256 + threadIdx.x;
  if (e >= NE) return;
  int src = ei[e];
  int dst = ei[NE + e];
  unsigned code = (unsigned)(ea[e * 3] | (ea[e * 3 + 1] << 3) | (ea[e * 3 + 2] << 6));
  int pos = atomicAdd(&fill[dst], 1);
  epack[pos] = (unsigned)src | (code << 17);
}

// ------------- K1: bond-encode + gather + relu + segsum + GIN -> z -------------
__global__ __launch_bounds__(256) void k_agg(const float* __restrict__ h,
                                             const float* __restrict__ bemb,
                                             const float* __restrict__ eps, int l,
                                             const int* __restrict__ row_ptr,
                                             const unsigned* __restrict__ epack,
                                             float* __restrict__ z) {
  __shared__ float tab[NBF * 8 * 64];  // 6 KB
  const float* bt = bemb + (size_t)l * NBF * 8 * 64;
  for (int i = threadIdx.x; i < NBF * 8 * 64; i += 256) tab[i] = bt[i];
  __syncthreads();
  int node = (blockIdx.x * 256 + threadIdx.x) >> 6;
  int lane = threadIdx.x & 63;
  if (node >= NN) return;
  int beg = row_ptr[node], end = row_ptr[node + 1];
  float acc = (1.0f + eps[l]) * h[(size_t)node * 64 + lane];
  for (int i = beg; i < end; ++i) {
    unsigned p = epack[i];
    int src = (int)(p & 0x1FFFFu);
    unsigned code = p >> 17;
    float e = tab[(code & 7) * 64 + lane]
            + tab[512 + ((code >> 3) & 7) * 64 + lane]
            + tab[1024 + ((code >> 6) & 7) * 64 + lane];
    float m = h[(size_t)src * 64 + lane] + e;
    acc += fmaxf(m, 0.f);
  }
  z[(size_t)node * 64 + lane] = acc;
}

// ------------- K2: z @ w1 + b1 -> y ; accumulate BN1 stats -------------
__global__ __launch_bounds__(256) void k_gemm1(const float* __restrict__ z,
                                               const float* __restrict__ w1,
                                               const float* __restrict__ b1,
                                               int l,
                                               float* __restrict__ y,
                                               float* __restrict__ stats) {
  int lane = threadIdx.x & 63;
  int wid = threadIdx.x >> 6;
  const float* w = w1 + (size_t)l * 64 * 128;
  float wr0[64], wr1[64];  // weight columns (lane, 64+lane) in registers
#pragma unroll
  for (int k = 0; k < 64; ++k) {
    wr0[k] = w[k * 128 + lane];
    wr1[k] = w[k * 128 + 64 + lane];
  }
  float bias0 = b1[l * 128 + lane];
  float bias1 = b1[l * 128 + 64 + lane];
  int gw = blockIdx.x * 4 + wid;
  int nw = gridDim.x * 4;
  float s0 = 0, s1 = 0, q0 = 0, q1 = 0;
  for (int row = gw; row < NN; row += nw) {
    float zv = z[(size_t)row * 64 + lane];
    float a0 = bias0, a1 = bias1;
#pragma unroll
    for (int k = 0; k < 64; ++k) {
      float zk = bcastf(zv, k);
      a0 = fmaf(zk, wr0[k], a0);
      a1 = fmaf(zk, wr1[k], a1);
    }
    y[(size_t)row * 128 + lane] = a0;
    y[(size_t)row * 128 + 64 + lane] = a1;
    s0 += a0; s1 += a1;
    q0 = fmaf(a0, a0, q0); q1 = fmaf(a1, a1, q1);
  }
  __shared__ float red[4][64][4];
  red[wid][lane][0] = s0; red[wid][lane][1] = s1;
  red[wid][lane][2] = q0; red[wid][lane][3] = q1;
  __syncthreads();
  if (wid == 0) {
    float t0 = 0, t1 = 0, t2 = 0, t3 = 0;
    for (int w2 = 0; w2 < 4; ++w2) {
      t0 += red[w2][lane][0]; t1 += red[w2][lane][1];
      t2 += red[w2][lane][2]; t3 += red[w2][lane][3];
    }
    atomicAdd(&stats[lane], t0);
    atomicAdd(&stats[64 + lane], t1);
    atomicAdd(&stats[128 + lane], t2);
    atomicAdd(&stats[192 + lane], t3);
  }
}

// ---- K3: y -> BN1 apply + relu -> @ w2 + b2 -> z2 ; accumulate BN2 stats ----
__global__ __launch_bounds__(256) void k_gemm2(const float* __restrict__ y,
                                               const float* __restrict__ w2,
                                               const float* __restrict__ b2,
                                               const float* __restrict__ g1,
                                               const float* __restrict__ bb1,
                                               int l,
                                               float* __restrict__ z2,
                                               float* __restrict__ stats) {
  __shared__ float ns[128], nb[128];
  if (threadIdx.x < 128) {
    int c = threadIdx.x;
    const float inv = 1.0f / NN;
    float mu = stats[c] * inv;
    float var = stats[128 + c] * inv - mu * mu;
    float sc = rsqrtf(var + BN_EPS) * g1[l * 128 + c];
    ns[c] = sc;
    nb[c] = bb1[l * 128 + c] - mu * sc;
  }
  __syncthreads();
  int lane = threadIdx.x & 63;
  int wid = threadIdx.x >> 6;
  const float* w = w2 + (size_t)l * 128 * 64;
  float wr[128];  // full weight column in registers
#pragma unroll
  for (int k = 0; k < 128; ++k) wr[k] = w[k * 64 + lane];
  float bias = b2[l * 64 + lane];
  float ns0 = ns[lane], nb0 = nb[lane];
  float ns1 = ns[64 + lane], nb1 = nb[64 + lane];
  int gw = blockIdx.x * 4 + wid;
  int nw = gridDim.x * 4;
  float s = 0, q = 0;
  for (int row = gw; row < NN; row += nw) {
    float y0 = y[(size_t)row * 128 + lane];
    float y1 = y[(size_t)row * 128 + 64 + lane];
    y0 = fmaxf(fmaf(y0, ns0, nb0), 0.f);
    y1 = fmaxf(fmaf(y1, ns1, nb1), 0.f);
    float a = bias;
#pragma unroll
    for (int k = 0; k < 64; ++k) a = fmaf(bcastf(y0, k), wr[k], a);
#pragma unroll
    for (int k = 0; k < 64; ++k) a = fmaf(bcastf(y1, k), wr[64 + k], a);
    z2[(size_t)row * 64 + lane] = a;
    s += a; q = fmaf(a, a, q);
  }
  __shared__ float red[4][64][2];
  red[wid][lane][0] = s; red[wid][lane][1] = q;
  __syncthreads();
  if (wid == 0) {
    float t0 = 0, t1 = 0;
    for (int w3 = 0; w3 < 4; ++w3) { t0 += red[w3][lane][0]; t1 += red[w3][lane][1]; }
    atomicAdd(&stats[256 + lane], t0);
    atomicAdd(&stats[320 + lane], t1);
  }
}

// ------------- K4: BN2 apply (+relu) -> h -------------
__global__ __launch_bounds__(256) void k_bn2(const float* __restrict__ z2,
                                             const float* __restrict__ g,
                                             const float* __restrict__ b,
                                             int l, int do_relu,
                                             const float* __restrict__ stats,
                                             float* __restrict__ h) {
  __shared__ float ns[64], nb[64];
  if (threadIdx.x < 64) {
    int c = threadIdx.x;
    const float inv = 1.0f / NN;
    float mu = stats[256 + c] * inv;
    float var = stats[320 + c] * inv - mu * mu;
    float sc = rsqrtf(var + BN_EPS) * g[l * 64 + c];
    ns[c] = sc;
    nb[c] = b[l * 64 + c] - mu * sc;
  }
  __syncthreads();
  const float4* zin = (const float4*)z2;
  float4* hout = (float4*)h;
  int total = NN * 16;  // float4 elements
  for (int i = blockIdx.x * 256 + threadIdx.x; i < total; i += gridDim.x * 256) {
    float4 v = zin[i];
    int c = (i & 15) * 4;
    v.x = fmaf(v.x, ns[c], nb[c]);
    v.y = fmaf(v.y, ns[c + 1], nb[c + 1]);
    v.z = fmaf(v.z, ns[c + 2], nb[c + 2]);
    v.w = fmaf(v.w, ns[c + 3], nb[c + 3]);
    if (do_relu) {
      v.x = fmaxf(v.x, 0.f); v.y = fmaxf(v.y, 0.f);
      v.z = fmaxf(v.z, 0.f); v.w = fmaxf(v.w, 0.f);
    }
    hout[i] = v;
  }
}

extern "C" void kernel_launch(void* const* d_in, const int* in_sizes, int n_in,
                              void* d_out, int out_size, void* d_ws, size_t ws_size,
                              hipStream_t stream) {
  const int* x = (const int*)d_in[0];
  const int* ei = (const int*)d_in[1];
  const int* ea = (const int*)d_in[2];
  const float* aemb = (const float*)d_in[3];
  const float* bemb = (const float*)d_in[4];
  const float* l1w = (const float*)d_in[5];
  const float* l1b = (const float*)d_in[6];
  const float* g1 = (const float*)d_in[7];
  const float* bb1 = (const float*)d_in[8];
  const float* l2w = (const float*)d_in[9];
  const float* l2b = (const float*)d_in[10];
  const float* eps = (const float*)d_in[11];
  const float* bng = (const float*)d_in[12];
  const float* bnb = (const float*)d_in[13];
  float* h = (float*)d_out;  // h lives in d_out across layers

  char* p = (char*)d_ws;
  float* z = (float*)p;            p += (size_t)NN * 64 * 4;
  float* y = (float*)p;            p += (size_t)NN * 128 * 4;
  unsigned* epack = (unsigned*)p;  p += (size_t)NE * 4;
  int* row_ptr = (int*)p;          p += (size_t)(NN + 1) * 4;
  int* fill = (int*)p;             p += (size_t)NN * 4;
  int* counts = (int*)p;           p += (size_t)NN * 4;
  float* stats = (float*)p;        p += 384 * 4;

  // CSR build (edge structure is layer-invariant)
  hipMemsetAsync(counts, 0, (size_t)NN * 4, stream);
  k_hist<<<(NE + 255) / 256, 256, 0, stream>>>(ei, counts);
  k_scan<<<1, 1024, 0, stream>>>(counts, row_ptr, fill);
  k_scatter<<<(NE + 255) / 256, 256, 0, stream>>>(ei, ea, fill, epack);

  k_atom<<<NN / 4, 256, 0, stream>>>(x, aemb, h);

  for (int l = 0; l < 4; ++l) {
    hipMemsetAsync(stats, 0, 384 * 4, stream);
    k_agg<<<NN / 4, 256, 0, stream>>>(h, bemb, eps, l, row_ptr, epack, z);
    k_gemm1<<<1024, 256, 0, stream>>>(z, l1w, l1b, l, y, stats);
    k_gemm2<<<1024, 256, 0, stream>>>(y, l2w, l2b, g1, bb1, l, z, stats);
    k_bn2<<<1024, 256, 0, stream>>>(z, bng, bnb, l, (l < 3) ? 1 : 0, stats, h);
  }
}

// Round 2
// 687.305 us; speedup vs baseline: 1.4120x; 1.4120x over previous
//
#include <hip/hip_runtime.h>
#include <hip/hip_bf16.h>

#define NN 50000
#define NE 800000
#define NAF 9
#define NBF 3
#define BN_EPS 1e-5f

__device__ __forceinline__ float bcastf(float v, int k) {
  return __int_as_float(__builtin_amdgcn_readlane(__float_as_int(v), k));
}

// ---------------- K0: atom encoder (sum of 9 embedding rows) ----------------
__global__ __launch_bounds__(256) void k_atom(const int* __restrict__ x,
                                              const float* __restrict__ aemb,
                                              float* __restrict__ h) {
  int node = (blockIdx.x * 256 + threadIdx.x) >> 6;
  int lane = threadIdx.x & 63;
  if (node >= NN) return;
  const int* xr = x + node * NAF;
  float acc = 0.f;
#pragma unroll
  for (int f = 0; f < NAF; ++f) {
    acc += aemb[(f * 64 + xr[f]) * 64 + lane];
  }
  h[(size_t)node * 64 + lane] = acc;
}

// ---------------- CSR build ----------------
__global__ __launch_bounds__(256) void k_hist(const int* __restrict__ ei,
                                              int* __restrict__ counts) {
  int e = blockIdx.x * 256 + threadIdx.x;
  if (e < NE) atomicAdd(&counts[ei[NE + e]], 1);
}

// Phase 1: per-block (256 nodes) exclusive partial scan + block sums
__global__ __launch_bounds__(256) void k_scan1(const int* __restrict__ counts,
                                               int* __restrict__ row_ptr,
                                               int* __restrict__ bsum) {
  int tid = threadIdx.x;
  int node = blockIdx.x * 256 + tid;
  int c = (node < NN) ? counts[node] : 0;
  int lane = tid & 63, wid = tid >> 6;
  int inc = c;
#pragma unroll
  for (int off = 1; off < 64; off <<= 1) {
    int t = __shfl_up(inc, off);
    if (lane >= off) inc += t;
  }
  __shared__ int wt[4];
  if (lane == 63) wt[wid] = inc;
  __syncthreads();
  int woff = 0;
#pragma unroll
  for (int w = 0; w < 4; ++w) woff += (w < wid) ? wt[w] : 0;
  int excl = inc - c + woff;
  if (node < NN) row_ptr[node] = excl;  // partial (missing inter-block offset)
  if (tid == 255) bsum[blockIdx.x] = woff + inc;  // block total
}

// Phase 2: single-block exclusive scan of block sums (196 entries)
__global__ __launch_bounds__(256) void k_scan2(const int* __restrict__ bsum,
                                               int* __restrict__ boff, int nb) {
  int tid = threadIdx.x;
  int c = (tid < nb) ? bsum[tid] : 0;
  int lane = tid & 63, wid = tid >> 6;
  int inc = c;
#pragma unroll
  for (int off = 1; off < 64; off <<= 1) {
    int t = __shfl_up(inc, off);
    if (lane >= off) inc += t;
  }
  __shared__ int wt[4];
  if (lane == 63) wt[wid] = inc;
  __syncthreads();
  int woff = 0;
#pragma unroll
  for (int w = 0; w < 4; ++w) woff += (w < wid) ? wt[w] : 0;
  if (tid < nb) boff[tid] = inc - c + woff;
}

// Phase 3: add block offsets, produce final row_ptr and fill cursor
__global__ __launch_bounds__(256) void k_scan3(int* __restrict__ row_ptr,
                                               const int* __restrict__ boff,
                                               int* __restrict__ fill) {
  int node = blockIdx.x * 256 + threadIdx.x;
  if (node < NN) {
    int r = row_ptr[node] + boff[blockIdx.x];
    row_ptr[node] = r;
    fill[node] = r;
  }
  if (node == 0) row_ptr[NN] = NE;
}

__global__ __launch_bounds__(256) void k_scatter(const int* __restrict__ ei,
                                                 const int* __restrict__ ea,
                                                 int* __restrict__ fill,
                                                 unsigned* __restrict__ epack) {
  int e = blockIdx.x * 256 + threadIdx.x;
  if (e >= NE) return;
  int src = ei[e];
  int dst = ei[NE + e];
  unsigned code = (unsigned)(ea[e * 3] | (ea[e * 3 + 1] << 3) | (ea[e * 3 + 2] << 6));
  int pos = atomicAdd(&fill[dst], 1);
  epack[pos] = (unsigned)src | (code << 17);
}

// ------------- K1: bond-encode + gather + relu + segsum + GIN -> z -------------
// Wave = 1 node. Lane = g*16 + c4: g in [0,4) = edge subgroup, c4 = channel/4.
// Each group strides edges by 4, unrolled x2 -> 8 independent gathers in flight.
__global__ __launch_bounds__(256) void k_agg(const float* __restrict__ h,
                                             const float* __restrict__ bemb,
                                             const float* __restrict__ eps, int l,
                                             const int* __restrict__ row_ptr,
                                             const unsigned* __restrict__ epack,
                                             float* __restrict__ z) {
  __shared__ float tab[NBF * 8 * 64];  // 6 KB
  const float* bt = bemb + (size_t)l * NBF * 8 * 64;
  for (int i = threadIdx.x; i < NBF * 8 * 64; i += 256) tab[i] = bt[i];
  __syncthreads();
  const float4* tab4 = (const float4*)tab;
  const float4* h4 = (const float4*)h;

  int node = (blockIdx.x * 256 + threadIdx.x) >> 6;
  int lane = threadIdx.x & 63;
  if (node >= NN) return;
  int g = lane >> 4;    // edge subgroup 0..3
  int c4 = lane & 15;   // channel quad 0..15

  int beg = row_ptr[node], end = row_ptr[node + 1];
  float4 acc = {0.f, 0.f, 0.f, 0.f};

  int i = beg + g;
  for (; i + 4 < end; i += 8) {
    unsigned p0 = epack[i];
    unsigned p1 = epack[i + 4];
    float4 m0 = h4[(size_t)(p0 & 0x1FFFFu) * 16 + c4];
    float4 m1 = h4[(size_t)(p1 & 0x1FFFFu) * 16 + c4];
    unsigned cd0 = p0 >> 17, cd1 = p1 >> 17;
    float4 e0a = tab4[(cd0 & 7) * 16 + c4];
    float4 e0b = tab4[128 + ((cd0 >> 3) & 7) * 16 + c4];
    float4 e0c = tab4[256 + ((cd0 >> 6) & 7) * 16 + c4];
    float4 e1a = tab4[(cd1 & 7) * 16 + c4];
    float4 e1b = tab4[128 + ((cd1 >> 3) & 7) * 16 + c4];
    float4 e1c = tab4[256 + ((cd1 >> 6) & 7) * 16 + c4];
    acc.x += fmaxf(m0.x + e0a.x + e0b.x + e0c.x, 0.f) + fmaxf(m1.x + e1a.x + e1b.x + e1c.x, 0.f);
    acc.y += fmaxf(m0.y + e0a.y + e0b.y + e0c.y, 0.f) + fmaxf(m1.y + e1a.y + e1b.y + e1c.y, 0.f);
    acc.z += fmaxf(m0.z + e0a.z + e0b.z + e0c.z, 0.f) + fmaxf(m1.z + e1a.z + e1b.z + e1c.z, 0.f);
    acc.w += fmaxf(m0.w + e0a.w + e0b.w + e0c.w, 0.f) + fmaxf(m1.w + e1a.w + e1b.w + e1c.w, 0.f);
  }
  if (i < end) {
    unsigned p0 = epack[i];
    float4 m0 = h4[(size_t)(p0 & 0x1FFFFu) * 16 + c4];
    unsigned cd0 = p0 >> 17;
    float4 e0a = tab4[(cd0 & 7) * 16 + c4];
    float4 e0b = tab4[128 + ((cd0 >> 3) & 7) * 16 + c4];
    float4 e0c = tab4[256 + ((cd0 >> 6) & 7) * 16 + c4];
    acc.x += fmaxf(m0.x + e0a.x + e0b.x + e0c.x, 0.f);
    acc.y += fmaxf(m0.y + e0a.y + e0b.y + e0c.y, 0.f);
    acc.z += fmaxf(m0.z + e0a.z + e0b.z + e0c.z, 0.f);
    acc.w += fmaxf(m0.w + e0a.w + e0b.w + e0c.w, 0.f);
  }
  // reduce across the 4 edge subgroups (lanes differing in bits 4,5)
#pragma unroll
  for (int off = 16; off <= 32; off <<= 1) {
    acc.x += __shfl_xor(acc.x, off);
    acc.y += __shfl_xor(acc.y, off);
    acc.z += __shfl_xor(acc.z, off);
    acc.w += __shfl_xor(acc.w, off);
  }
  if (g == 0) {
    float4 self = h4[(size_t)node * 16 + c4];
    float se = 1.0f + eps[l];
    float4 out;
    out.x = fmaf(self.x, se, acc.x);
    out.y = fmaf(self.y, se, acc.y);
    out.z = fmaf(self.z, se, acc.z);
    out.w = fmaf(self.w, se, acc.w);
    ((float4*)z)[(size_t)node * 16 + c4] = out;
  }
}

// ------------- K2: z @ w1 + b1 -> y ; accumulate BN1 stats -------------
__global__ __launch_bounds__(256) void k_gemm1(const float* __restrict__ z,
                                               const float* __restrict__ w1,
                                               const float* __restrict__ b1,
                                               int l,
                                               float* __restrict__ y,
                                               float* __restrict__ stats) {
  int lane = threadIdx.x & 63;
  int wid = threadIdx.x >> 6;
  const float* w = w1 + (size_t)l * 64 * 128;
  float wr0[64], wr1[64];
#pragma unroll
  for (int k = 0; k < 64; ++k) {
    wr0[k] = w[k * 128 + lane];
    wr1[k] = w[k * 128 + 64 + lane];
  }
  float bias0 = b1[l * 128 + lane];
  float bias1 = b1[l * 128 + 64 + lane];
  int gw = blockIdx.x * 4 + wid;
  int nw = gridDim.x * 4;
  float s0 = 0, s1 = 0, q0 = 0, q1 = 0;
  for (int row = gw; row < NN; row += nw) {
    float zv = z[(size_t)row * 64 + lane];
    float a0 = bias0, a1 = bias1;
#pragma unroll
    for (int k = 0; k < 64; ++k) {
      float zk = bcastf(zv, k);
      a0 = fmaf(zk, wr0[k], a0);
      a1 = fmaf(zk, wr1[k], a1);
    }
    y[(size_t)row * 128 + lane] = a0;
    y[(size_t)row * 128 + 64 + lane] = a1;
    s0 += a0; s1 += a1;
    q0 = fmaf(a0, a0, q0); q1 = fmaf(a1, a1, q1);
  }
  __shared__ float red[4][64][4];
  red[wid][lane][0] = s0; red[wid][lane][1] = s1;
  red[wid][lane][2] = q0; red[wid][lane][3] = q1;
  __syncthreads();
  if (wid == 0) {
    float t0 = 0, t1 = 0, t2 = 0, t3 = 0;
    for (int w2 = 0; w2 < 4; ++w2) {
      t0 += red[w2][lane][0]; t1 += red[w2][lane][1];
      t2 += red[w2][lane][2]; t3 += red[w2][lane][3];
    }
    atomicAdd(&stats[lane], t0);
    atomicAdd(&stats[64 + lane], t1);
    atomicAdd(&stats[128 + lane], t2);
    atomicAdd(&stats[192 + lane], t3);
  }
}

// ---- K3: y -> BN1 apply + relu -> @ w2 + b2 -> z2 ; accumulate BN2 stats ----
__global__ __launch_bounds__(256) void k_gemm2(const float* __restrict__ y,
                                               const float* __restrict__ w2,
                                               const float* __restrict__ b2,
                                               const float* __restrict__ g1,
                                               const float* __restrict__ bb1,
                                               int l,
                                               float* __restrict__ z2,
                                               float* __restrict__ stats) {
  __shared__ float ns[128], nb[128];
  if (threadIdx.x < 128) {
    int c = threadIdx.x;
    const float inv = 1.0f / NN;
    float mu = stats[c] * inv;
    float var = stats[128 + c] * inv - mu * mu;
    float sc = rsqrtf(var + BN_EPS) * g1[l * 128 + c];
    ns[c] = sc;
    nb[c] = bb1[l * 128 + c] - mu * sc;
  }
  __syncthreads();
  int lane = threadIdx.x & 63;
  int wid = threadIdx.x >> 6;
  const float* w = w2 + (size_t)l * 128 * 64;
  float wr[128];
#pragma unroll
  for (int k = 0; k < 128; ++k) wr[k] = w[k * 64 + lane];
  float bias = b2[l * 64 + lane];
  float ns0 = ns[lane], nb0 = nb[lane];
  float ns1 = ns[64 + lane], nb1 = nb[64 + lane];
  int gw = blockIdx.x * 4 + wid;
  int nw = gridDim.x * 4;
  float s = 0, q = 0;
  for (int row = gw; row < NN; row += nw) {
    float y0 = y[(size_t)row * 128 + lane];
    float y1 = y[(size_t)row * 128 + 64 + lane];
    y0 = fmaxf(fmaf(y0, ns0, nb0), 0.f);
    y1 = fmaxf(fmaf(y1, ns1, nb1), 0.f);
    float a = bias;
#pragma unroll
    for (int k = 0; k < 64; ++k) a = fmaf(bcastf(y0, k), wr[k], a);
#pragma unroll
    for (int k = 0; k < 64; ++k) a = fmaf(bcastf(y1, k), wr[64 + k], a);
    z2[(size_t)row * 64 + lane] = a;
    s += a; q = fmaf(a, a, q);
  }
  __shared__ float red[4][64][2];
  red[wid][lane][0] = s; red[wid][lane][1] = q;
  __syncthreads();
  if (wid == 0) {
    float t0 = 0, t1 = 0;
    for (int w3 = 0; w3 < 4; ++w3) { t0 += red[w3][lane][0]; t1 += red[w3][lane][1]; }
    atomicAdd(&stats[256 + lane], t0);
    atomicAdd(&stats[320 + lane], t1);
  }
}

// ------------- K4: BN2 apply (+relu) -> h -------------
__global__ __launch_bounds__(256) void k_bn2(const float* __restrict__ z2,
                                             const float* __restrict__ g,
                                             const float* __restrict__ b,
                                             int l, int do_relu,
                                             const float* __restrict__ stats,
                                             float* __restrict__ h) {
  __shared__ float ns[64], nb[64];
  if (threadIdx.x < 64) {
    int c = threadIdx.x;
    const float inv = 1.0f / NN;
    float mu = stats[256 + c] * inv;
    float var = stats[320 + c] * inv - mu * mu;
    float sc = rsqrtf(var + BN_EPS) * g[l * 64 + c];
    ns[c] = sc;
    nb[c] = b[l * 64 + c] - mu * sc;
  }
  __syncthreads();
  const float4* zin = (const float4*)z2;
  float4* hout = (float4*)h;
  int total = NN * 16;
  for (int i = blockIdx.x * 256 + threadIdx.x; i < total; i += gridDim.x * 256) {
    float4 v = zin[i];
    int c = (i & 15) * 4;
    v.x = fmaf(v.x, ns[c], nb[c]);
    v.y = fmaf(v.y, ns[c + 1], nb[c + 1]);
    v.z = fmaf(v.z, ns[c + 2], nb[c + 2]);
    v.w = fmaf(v.w, ns[c + 3], nb[c + 3]);
    if (do_relu) {
      v.x = fmaxf(v.x, 0.f); v.y = fmaxf(v.y, 0.f);
      v.z = fmaxf(v.z, 0.f); v.w = fmaxf(v.w, 0.f);
    }
    hout[i] = v;
  }
}

extern "C" void kernel_launch(void* const* d_in, const int* in_sizes, int n_in,
                              void* d_out, int out_size, void* d_ws, size_t ws_size,
                              hipStream_t stream) {
  const int* x = (const int*)d_in[0];
  const int* ei = (const int*)d_in[1];
  const int* ea = (const int*)d_in[2];
  const float* aemb = (const float*)d_in[3];
  const float* bemb = (const float*)d_in[4];
  const float* l1w = (const float*)d_in[5];
  const float* l1b = (const float*)d_in[6];
  const float* g1 = (const float*)d_in[7];
  const float* bb1 = (const float*)d_in[8];
  const float* l2w = (const float*)d_in[9];
  const float* l2b = (const float*)d_in[10];
  const float* eps = (const float*)d_in[11];
  const float* bng = (const float*)d_in[12];
  const float* bnb = (const float*)d_in[13];
  float* h = (float*)d_out;

  char* p = (char*)d_ws;
  float* z = (float*)p;            p += (size_t)NN * 64 * 4;
  float* y = (float*)p;            p += (size_t)NN * 128 * 4;
  unsigned* epack = (unsigned*)p;  p += (size_t)NE * 4;
  int* row_ptr = (int*)p;          p += (size_t)(NN + 1) * 4;
  int* fill = (int*)p;             p += (size_t)NN * 4;
  int* counts = (int*)p;           p += (size_t)NN * 4;
  float* stats = (float*)p;        p += 384 * 4;
  int* bsum = (int*)p;             p += 256 * 4;
  int* boff = (int*)p;             p += 256 * 4;

  const int NB = (NN + 255) / 256;  // 196 scan blocks

  // CSR build (edge structure is layer-invariant)
  hipMemsetAsync(counts, 0, (size_t)NN * 4, stream);
  k_hist<<<(NE + 255) / 256, 256, 0, stream>>>(ei, counts);
  k_scan1<<<NB, 256, 0, stream>>>(counts, row_ptr, bsum);
  k_scan2<<<1, 256, 0, stream>>>(bsum, boff, NB);
  k_scan3<<<NB, 256, 0, stream>>>(row_ptr, boff, fill);
  k_scatter<<<(NE + 255) / 256, 256, 0, stream>>>(ei, ea, fill, epack);

  k_atom<<<NN / 4, 256, 0, stream>>>(x, aemb, h);

  for (int l = 0; l < 4; ++l) {
    hipMemsetAsync(stats, 0, 384 * 4, stream);
    k_agg<<<NN / 4, 256, 0, stream>>>(h, bemb, eps, l, row_ptr, epack, z);
    k_gemm1<<<1024, 256, 0, stream>>>(z, l1w, l1b, l, y, stats);
    k_gemm2<<<1024, 256, 0, stream>>>(y, l2w, l2b, g1, bb1, l, z, stats);
    k_bn2<<<1024, 256, 0, stream>>>(z, bng, bnb, l, (l < 3) ? 1 : 0, stats, h);
  }
}

// Round 3
// 642.967 us; speedup vs baseline: 1.5094x; 1.0690x over previous
//
#include <hip/hip_runtime.h>
#include <hip/hip_bf16.h>

#define NN 50000
#define NE 800000
#define NAF 9
#define NBF 3
#define BN_EPS 1e-5f
#define NBUK 196          // ceil(NN/256) dst buckets
#define CHUNK 8192        // edges staged in LDS per k_bin block

__device__ __forceinline__ float bcastf(float v, int k) {
  return __int_as_float(__builtin_amdgcn_readlane(__float_as_int(v), k));
}

// ---------------- K0: atom encoder ----------------
__global__ __launch_bounds__(256) void k_atom(const int* __restrict__ x,
                                              const float* __restrict__ aemb,
                                              float* __restrict__ h) {
  int node = (blockIdx.x * 256 + threadIdx.x) >> 6;
  int lane = threadIdx.x & 63;
  if (node >= NN) return;
  const int* xr = x + node * NAF;
  float acc = 0.f;
#pragma unroll
  for (int f = 0; f < NAF; ++f) acc += aemb[(f * 64 + xr[f]) * 64 + lane];
  h[(size_t)node * 64 + lane] = acc;
}

// ---------------- CSR build, binned ----------------
// Pass 1: pack payload+dst pairs (coalesced), node hist, bucket hist.
__global__ __launch_bounds__(1024) void k_pack_hist(const int* __restrict__ ei,
                                                    const int* __restrict__ ea,
                                                    uint2* __restrict__ pairs,
                                                    int* __restrict__ counts,
                                                    int* __restrict__ bcnt) {
  __shared__ int lh[NBUK];
  for (int i = threadIdx.x; i < NBUK; i += 1024) lh[i] = 0;
  __syncthreads();
  for (int e = blockIdx.x * 1024 + threadIdx.x; e < NE; e += gridDim.x * 1024) {
    int src = ei[e];
    int dst = ei[NE + e];
    unsigned code = (unsigned)(ea[e * 3] | (ea[e * 3 + 1] << 3) | (ea[e * 3 + 2] << 6));
    pairs[e] = make_uint2((unsigned)src | (code << 17), (unsigned)dst);
    atomicAdd(&counts[dst], 1);
    atomicAdd(&lh[dst >> 8], 1);
  }
  __syncthreads();
  for (int i = threadIdx.x; i < NBUK; i += 1024)
    if (lh[i]) atomicAdd(&bcnt[i], lh[i]);
}

// Exclusive scan of bucket counts (NBUK <= 256), writes base and fill cursor.
__global__ __launch_bounds__(256) void k_scanb(const int* __restrict__ bcnt,
                                               int* __restrict__ bbase,
                                               int* __restrict__ bfill) {
  int tid = threadIdx.x;
  int c = (tid < NBUK) ? bcnt[tid] : 0;
  int lane = tid & 63, wid = tid >> 6;
  int inc = c;
#pragma unroll
  for (int off = 1; off < 64; off <<= 1) {
    int t = __shfl_up(inc, off);
    if (lane >= off) inc += t;
  }
  __shared__ int wt[4];
  if (lane == 63) wt[wid] = inc;
  __syncthreads();
  int woff = 0;
#pragma unroll
  for (int w = 0; w < 4; ++w) woff += (w < wid) ? wt[w] : 0;
  if (tid < NBUK) { int e = inc - c + woff; bbase[tid] = e; bfill[tid] = e; }
}

// Node-count scan (3-phase)
__global__ __launch_bounds__(256) void k_scan1(const int* __restrict__ counts,
                                               int* __restrict__ row_ptr,
                                               int* __restrict__ bsum) {
  int tid = threadIdx.x;
  int node = blockIdx.x * 256 + tid;
  int c = (node < NN) ? counts[node] : 0;
  int lane = tid & 63, wid = tid >> 6;
  int inc = c;
#pragma unroll
  for (int off = 1; off < 64; off <<= 1) {
    int t = __shfl_up(inc, off);
    if (lane >= off) inc += t;
  }
  __shared__ int wt[4];
  if (lane == 63) wt[wid] = inc;
  __syncthreads();
  int woff = 0;
#pragma unroll
  for (int w = 0; w < 4; ++w) woff += (w < wid) ? wt[w] : 0;
  if (node < NN) row_ptr[node] = inc - c + woff;
  if (tid == 255) bsum[blockIdx.x] = woff + inc;
}

__global__ __launch_bounds__(256) void k_scan2(const int* __restrict__ bsum,
                                               int* __restrict__ boff, int nb) {
  int tid = threadIdx.x;
  int c = (tid < nb) ? bsum[tid] : 0;
  int lane = tid & 63, wid = tid >> 6;
  int inc = c;
#pragma unroll
  for (int off = 1; off < 64; off <<= 1) {
    int t = __shfl_up(inc, off);
    if (lane >= off) inc += t;
  }
  __shared__ int wt[4];
  if (lane == 63) wt[wid] = inc;
  __syncthreads();
  int woff = 0;
#pragma unroll
  for (int w = 0; w < 4; ++w) woff += (w < wid) ? wt[w] : 0;
  if (tid < nb) boff[tid] = inc - c + woff;
}

__global__ __launch_bounds__(256) void k_scan3(int* __restrict__ row_ptr,
                                               const int* __restrict__ boff) {
  int node = blockIdx.x * 256 + threadIdx.x;
  if (node < NN) row_ptr[node] += boff[blockIdx.x];
  if (node == 0) row_ptr[NN] = NE;
}

// Pass 2: bin pairs by dst bucket. LDS-staged; dense global writes.
__global__ __launch_bounds__(1024) void k_bin(const uint2* __restrict__ pairs,
                                              int* __restrict__ bfill,
                                              uint2* __restrict__ binned) {
  __shared__ uint2 st[CHUNK];     // 64 KB
  __shared__ int lh[NBUK];
  __shared__ int gbase[NBUK];
  int tid = threadIdx.x;
  int base = blockIdx.x * CHUNK;
  int n = NE - base; if (n > CHUNK) n = CHUNK;
  for (int i = tid; i < NBUK; i += 1024) lh[i] = 0;
  __syncthreads();
  for (int i = tid; i < n; i += 1024) {
    uint2 p = pairs[base + i];
    st[i] = p;
    atomicAdd(&lh[p.y >> 8], 1);
  }
  __syncthreads();
  for (int i = tid; i < NBUK; i += 1024) {
    int c = lh[i];
    gbase[i] = c ? atomicAdd(&bfill[i], c) : 0;
  }
  __syncthreads();
  for (int i = tid; i < NBUK; i += 1024) lh[i] = 0;
  __syncthreads();
  for (int i = tid; i < n; i += 1024) {
    uint2 p = st[i];
    int b = p.y >> 8;
    int r = atomicAdd(&lh[b], 1);
    binned[gbase[b] + r] = p;
  }
}

// Pass 3: within-bucket scatter to CSR positions (L2-local ~16KB window).
__global__ __launch_bounds__(1024) void k_fin(const uint2* __restrict__ binned,
                                              const int* __restrict__ bbase,
                                              const int* __restrict__ bcnt,
                                              const int* __restrict__ row_ptr,
                                              unsigned* __restrict__ epack) {
  __shared__ int cur[256];
  int b = blockIdx.x;
  int tid = threadIdx.x;
  int node0 = b << 8;
  if (tid < 256) cur[tid] = (node0 + tid < NN) ? row_ptr[node0 + tid] : 0;
  __syncthreads();
  int s = bbase[b], n = bcnt[b];
  for (int i = tid; i < n; i += 1024) {
    uint2 p = binned[s + i];
    int pos = atomicAdd(&cur[p.y & 255], 1);
    epack[pos] = p.x;
  }
}

// ------------- aggregation (optionally BN+ReLU-fused input) -------------
template <bool BN>
__device__ __forceinline__ void agg_body(const float* __restrict__ hin,
                                         const float* __restrict__ bemb,
                                         const float* __restrict__ eps, int l,
                                         const int* __restrict__ row_ptr,
                                         const unsigned* __restrict__ epack,
                                         const float* __restrict__ stp,
                                         const float* __restrict__ g,
                                         const float* __restrict__ bb,
                                         float* __restrict__ z) {
  __shared__ float tab[NBF * 8 * 64];  // 6 KB
  __shared__ float nsb[128];           // ns[0..64), nb[64..128)
  const float* bt = bemb + (size_t)l * NBF * 8 * 64;
  for (int i = threadIdx.x; i < NBF * 8 * 64; i += 256) tab[i] = bt[i];
  if (BN && threadIdx.x < 64) {
    int c = threadIdx.x;
    const float inv = 1.0f / NN;
    float mu = stp[c] * inv;
    float var = stp[64 + c] * inv - mu * mu;
    float sc = rsqrtf(var + BN_EPS) * g[c];
    nsb[c] = sc;
    nsb[64 + c] = bb[c] - mu * sc;
  }
  __syncthreads();
  const float4* tab4 = (const float4*)tab;
  const float4* h4 = (const float4*)hin;

  int node = (blockIdx.x * 256 + threadIdx.x) >> 6;
  int lane = threadIdx.x & 63;
  if (node >= NN) return;
  int gr = lane >> 4;
  int c4 = lane & 15;
  float4 ns4 = {1.f, 1.f, 1.f, 1.f}, nb4 = {0.f, 0.f, 0.f, 0.f};
  if (BN) {
    ns4 = ((const float4*)nsb)[c4];
    nb4 = ((const float4*)(nsb + 64))[c4];
  }

  int beg = row_ptr[node], end = row_ptr[node + 1];
  float4 acc = {0.f, 0.f, 0.f, 0.f};

  int i = beg + gr;
  for (; i + 4 < end; i += 8) {
    unsigned p0 = epack[i];
    unsigned p1 = epack[i + 4];
    float4 m0 = h4[(size_t)(p0 & 0x1FFFFu) * 16 + c4];
    float4 m1 = h4[(size_t)(p1 & 0x1FFFFu) * 16 + c4];
    unsigned cd0 = p0 >> 17, cd1 = p1 >> 17;
    float4 e0a = tab4[(cd0 & 7) * 16 + c4];
    float4 e0b = tab4[128 + ((cd0 >> 3) & 7) * 16 + c4];
    float4 e0c = tab4[256 + ((cd0 >> 6) & 7) * 16 + c4];
    float4 e1a = tab4[(cd1 & 7) * 16 + c4];
    float4 e1b = tab4[128 + ((cd1 >> 3) & 7) * 16 + c4];
    float4 e1c = tab4[256 + ((cd1 >> 6) & 7) * 16 + c4];
    if (BN) {
      m0.x = fmaxf(fmaf(m0.x, ns4.x, nb4.x), 0.f); m1.x = fmaxf(fmaf(m1.x, ns4.x, nb4.x), 0.f);
      m0.y = fmaxf(fmaf(m0.y, ns4.y, nb4.y), 0.f); m1.y = fmaxf(fmaf(m1.y, ns4.y, nb4.y), 0.f);
      m0.z = fmaxf(fmaf(m0.z, ns4.z, nb4.z), 0.f); m1.z = fmaxf(fmaf(m1.z, ns4.z, nb4.z), 0.f);
      m0.w = fmaxf(fmaf(m0.w, ns4.w, nb4.w), 0.f); m1.w = fmaxf(fmaf(m1.w, ns4.w, nb4.w), 0.f);
    }
    acc.x += fmaxf(m0.x + e0a.x + e0b.x + e0c.x, 0.f) + fmaxf(m1.x + e1a.x + e1b.x + e1c.x, 0.f);
    acc.y += fmaxf(m0.y + e0a.y + e0b.y + e0c.y, 0.f) + fmaxf(m1.y + e1a.y + e1b.y + e1c.y, 0.f);
    acc.z += fmaxf(m0.z + e0a.z + e0b.z + e0c.z, 0.f) + fmaxf(m1.z + e1a.z + e1b.z + e1c.z, 0.f);
    acc.w += fmaxf(m0.w + e0a.w + e0b.w + e0c.w, 0.f) + fmaxf(m1.w + e1a.w + e1b.w + e1c.w, 0.f);
  }
  if (i < end) {
    unsigned p0 = epack[i];
    float4 m0 = h4[(size_t)(p0 & 0x1FFFFu) * 16 + c4];
    unsigned cd0 = p0 >> 17;
    float4 e0a = tab4[(cd0 & 7) * 16 + c4];
    float4 e0b = tab4[128 + ((cd0 >> 3) & 7) * 16 + c4];
    float4 e0c = tab4[256 + ((cd0 >> 6) & 7) * 16 + c4];
    if (BN) {
      m0.x = fmaxf(fmaf(m0.x, ns4.x, nb4.x), 0.f);
      m0.y = fmaxf(fmaf(m0.y, ns4.y, nb4.y), 0.f);
      m0.z = fmaxf(fmaf(m0.z, ns4.z, nb4.z), 0.f);
      m0.w = fmaxf(fmaf(m0.w, ns4.w, nb4.w), 0.f);
    }
    acc.x += fmaxf(m0.x + e0a.x + e0b.x + e0c.x, 0.f);
    acc.y += fmaxf(m0.y + e0a.y + e0b.y + e0c.y, 0.f);
    acc.z += fmaxf(m0.z + e0a.z + e0b.z + e0c.z, 0.f);
    acc.w += fmaxf(m0.w + e0a.w + e0b.w + e0c.w, 0.f);
  }
#pragma unroll
  for (int off = 16; off <= 32; off <<= 1) {
    acc.x += __shfl_xor(acc.x, off);
    acc.y += __shfl_xor(acc.y, off);
    acc.z += __shfl_xor(acc.z, off);
    acc.w += __shfl_xor(acc.w, off);
  }
  if (gr == 0) {
    float4 self = h4[(size_t)node * 16 + c4];
    if (BN) {
      self.x = fmaxf(fmaf(self.x, ns4.x, nb4.x), 0.f);
      self.y = fmaxf(fmaf(self.y, ns4.y, nb4.y), 0.f);
      self.z = fmaxf(fmaf(self.z, ns4.z, nb4.z), 0.f);
      self.w = fmaxf(fmaf(self.w, ns4.w, nb4.w), 0.f);
    }
    float se = 1.0f + eps[l];
    float4 out;
    out.x = fmaf(self.x, se, acc.x);
    out.y = fmaf(self.y, se, acc.y);
    out.z = fmaf(self.z, se, acc.z);
    out.w = fmaf(self.w, se, acc.w);
    ((float4*)z)[(size_t)node * 16 + c4] = out;
  }
}

__global__ __launch_bounds__(256) void k_agg0(const float* __restrict__ hin,
                                              const float* __restrict__ bemb,
                                              const float* __restrict__ eps, int l,
                                              const int* __restrict__ row_ptr,
                                              const unsigned* __restrict__ epack,
                                              float* __restrict__ z) {
  agg_body<false>(hin, bemb, eps, l, row_ptr, epack, nullptr, nullptr, nullptr, z);
}

__global__ __launch_bounds__(256) void k_aggbn(const float* __restrict__ hin,
                                               const float* __restrict__ bemb,
                                               const float* __restrict__ eps, int l,
                                               const int* __restrict__ row_ptr,
                                               const unsigned* __restrict__ epack,
                                               const float* __restrict__ stp,
                                               const float* __restrict__ g,
                                               const float* __restrict__ bb,
                                               float* __restrict__ z) {
  agg_body<true>(hin, bemb, eps, l, row_ptr, epack, stp, g, bb, z);
}

// ------------- gemm1: z @ w1 + b1 -> y ; BN1 stats -------------
__global__ __launch_bounds__(256) void k_gemm1(const float* __restrict__ z,
                                               const float* __restrict__ w1,
                                               const float* __restrict__ b1,
                                               int l,
                                               float* __restrict__ y,
                                               float* __restrict__ st1) {
  int lane = threadIdx.x & 63;
  int wid = threadIdx.x >> 6;
  const float* w = w1 + (size_t)l * 64 * 128;
  float wr0[64], wr1[64];
#pragma unroll
  for (int k = 0; k < 64; ++k) {
    wr0[k] = w[k * 128 + lane];
    wr1[k] = w[k * 128 + 64 + lane];
  }
  float bias0 = b1[l * 128 + lane];
  float bias1 = b1[l * 128 + 64 + lane];
  int gw = blockIdx.x * 4 + wid;
  int nw = gridDim.x * 4;
  float s0 = 0, s1 = 0, q0 = 0, q1 = 0;
  for (int row = gw; row < NN; row += nw) {
    float zv = z[(size_t)row * 64 + lane];
    float a0 = bias0, a1 = bias1;
#pragma unroll
    for (int k = 0; k < 64; ++k) {
      float zk = bcastf(zv, k);
      a0 = fmaf(zk, wr0[k], a0);
      a1 = fmaf(zk, wr1[k], a1);
    }
    y[(size_t)row * 128 + lane] = a0;
    y[(size_t)row * 128 + 64 + lane] = a1;
    s0 += a0; s1 += a1;
    q0 = fmaf(a0, a0, q0); q1 = fmaf(a1, a1, q1);
  }
  __shared__ float red[4][64][4];
  red[wid][lane][0] = s0; red[wid][lane][1] = s1;
  red[wid][lane][2] = q0; red[wid][lane][3] = q1;
  __syncthreads();
  if (wid == 0) {
    float t0 = 0, t1 = 0, t2 = 0, t3 = 0;
    for (int w2 = 0; w2 < 4; ++w2) {
      t0 += red[w2][lane][0]; t1 += red[w2][lane][1];
      t2 += red[w2][lane][2]; t3 += red[w2][lane][3];
    }
    atomicAdd(&st1[lane], t0);
    atomicAdd(&st1[64 + lane], t1);
    atomicAdd(&st1[128 + lane], t2);
    atomicAdd(&st1[192 + lane], t3);
  }
}

// ---- gemm2: BN1-apply + relu -> @ w2 + b2 -> z2 ; BN2 stats ----
__global__ __launch_bounds__(256) void k_gemm2(const float* __restrict__ y,
                                               const float* __restrict__ w2,
                                               const float* __restrict__ b2,
                                               const float* __restrict__ g1,
                                               const float* __restrict__ bb1,
                                               int l,
                                               float* __restrict__ z2,
                                               const float* __restrict__ st1,
                                               float* __restrict__ st2) {
  __shared__ float ns[128], nb[128];
  if (threadIdx.x < 128) {
    int c = threadIdx.x;
    const float inv = 1.0f / NN;
    float mu = st1[c] * inv;
    float var = st1[128 + c] * inv - mu * mu;
    float sc = rsqrtf(var + BN_EPS) * g1[l * 128 + c];
    ns[c] = sc;
    nb[c] = bb1[l * 128 + c] - mu * sc;
  }
  __syncthreads();
  int lane = threadIdx.x & 63;
  int wid = threadIdx.x >> 6;
  const float* w = w2 + (size_t)l * 128 * 64;
  float wr[128];
#pragma unroll
  for (int k = 0; k < 128; ++k) wr[k] = w[k * 64 + lane];
  float bias = b2[l * 64 + lane];
  float ns0 = ns[lane], nb0 = nb[lane];
  float ns1 = ns[64 + lane], nb1 = nb[64 + lane];
  int gw = blockIdx.x * 4 + wid;
  int nw = gridDim.x * 4;
  float s = 0, q = 0;
  for (int row = gw; row < NN; row += nw) {
    float y0 = y[(size_t)row * 128 + lane];
    float y1 = y[(size_t)row * 128 + 64 + lane];
    y0 = fmaxf(fmaf(y0, ns0, nb0), 0.f);
    y1 = fmaxf(fmaf(y1, ns1, nb1), 0.f);
    float a = bias;
#pragma unroll
    for (int k = 0; k < 64; ++k) a = fmaf(bcastf(y0, k), wr[k], a);
#pragma unroll
    for (int k = 0; k < 64; ++k) a = fmaf(bcastf(y1, k), wr[64 + k], a);
    z2[(size_t)row * 64 + lane] = a;
    s += a; q = fmaf(a, a, q);
  }
  __shared__ float red[4][64][2];
  red[wid][lane][0] = s; red[wid][lane][1] = q;
  __syncthreads();
  if (wid == 0) {
    float t0 = 0, t1 = 0;
    for (int w3 = 0; w3 < 4; ++w3) { t0 += red[w3][lane][0]; t1 += red[w3][lane][1]; }
    atomicAdd(&st2[lane], t0);
    atomicAdd(&st2[64 + lane], t1);
  }
}

// ------------- final BN2 apply (no relu) -> d_out -------------
__global__ __launch_bounds__(256) void k_bn2(const float* __restrict__ z2,
                                             const float* __restrict__ g,
                                             const float* __restrict__ b,
                                             const float* __restrict__ st,
                                             float* __restrict__ h) {
  __shared__ float ns[64], nb[64];
  if (threadIdx.x < 64) {
    int c = threadIdx.x;
    const float inv = 1.0f / NN;
    float mu = st[c] * inv;
    float var = st[64 + c] * inv - mu * mu;
    float sc = rsqrtf(var + BN_EPS) * g[c];
    ns[c] = sc;
    nb[c] = b[c] - mu * sc;
  }
  __syncthreads();
  const float4* zin = (const float4*)z2;
  float4* hout = (float4*)h;
  int total = NN * 16;
  for (int i = blockIdx.x * 256 + threadIdx.x; i < total; i += gridDim.x * 256) {
    float4 v = zin[i];
    int c = (i & 15) * 4;
    v.x = fmaf(v.x, ns[c], nb[c]);
    v.y = fmaf(v.y, ns[c + 1], nb[c + 1]);
    v.z = fmaf(v.z, ns[c + 2], nb[c + 2]);
    v.w = fmaf(v.w, ns[c + 3], nb[c + 3]);
    hout[i] = v;
  }
}

extern "C" void kernel_launch(void* const* d_in, const int* in_sizes, int n_in,
                              void* d_out, int out_size, void* d_ws, size_t ws_size,
                              hipStream_t stream) {
  const int* x = (const int*)d_in[0];
  const int* ei = (const int*)d_in[1];
  const int* ea = (const int*)d_in[2];
  const float* aemb = (const float*)d_in[3];
  const float* bemb = (const float*)d_in[4];
  const float* l1w = (const float*)d_in[5];
  const float* l1b = (const float*)d_in[6];
  const float* g1 = (const float*)d_in[7];
  const float* bb1 = (const float*)d_in[8];
  const float* l2w = (const float*)d_in[9];
  const float* l2b = (const float*)d_in[10];
  const float* eps = (const float*)d_in[11];
  const float* bng = (const float*)d_in[12];
  const float* bnb = (const float*)d_in[13];
  float* out = (float*)d_out;

  char* p = (char*)d_ws;
  float* zA = (float*)p;           p += (size_t)NN * 64 * 4;    // agg out; pairs alias
  float* y = (float*)p;            p += (size_t)NN * 128 * 4;   // gemm1 out; binned alias
  float* zB = (float*)p;           p += (size_t)NN * 64 * 4;    // gemm2 out; h0 alias
  unsigned* epack = (unsigned*)p;  p += (size_t)NE * 4;
  int* row_ptr = (int*)p;          p += (size_t)(NN + 1) * 4;
  int* counts = (int*)p;           p += (size_t)NN * 4;
  int* bcnt = (int*)p;             p += 256 * 4;
  int* bbase = (int*)p;            p += 256 * 4;
  int* bfill = (int*)p;            p += 256 * 4;
  float* stats = (float*)p;        p += 4 * 384 * 4;
  int* bsum = (int*)p;             p += 256 * 4;
  int* boff = (int*)p;             p += 256 * 4;

  uint2* pairs = (uint2*)zA;   // dead before first k_agg0 (CSR phase only)
  uint2* binned = (uint2*)y;   // dead before first k_gemm1
  float* h0 = zB;              // dead after k_agg0, before first k_gemm2 write

  const int NB = (NN + 255) / 256;  // 196

  hipMemsetAsync(counts, 0, (size_t)NN * 4, stream);
  hipMemsetAsync(bcnt, 0, 256 * 4, stream);
  hipMemsetAsync(stats, 0, 4 * 384 * 4, stream);

  k_pack_hist<<<256, 1024, 0, stream>>>(ei, ea, pairs, counts, bcnt);
  k_scanb<<<1, 256, 0, stream>>>(bcnt, bbase, bfill);
  k_scan1<<<NB, 256, 0, stream>>>(counts, row_ptr, bsum);
  k_scan2<<<1, 256, 0, stream>>>(bsum, boff, NB);
  k_scan3<<<NB, 256, 0, stream>>>(row_ptr, boff);
  k_bin<<<(NE + CHUNK - 1) / CHUNK, 1024, 0, stream>>>(pairs, bfill, binned);
  k_fin<<<NBUK, 1024, 0, stream>>>(binned, bbase, bcnt, row_ptr, epack);

  k_atom<<<NN / 4, 256, 0, stream>>>(x, aemb, h0);

  for (int l = 0; l < 4; ++l) {
    float* st1 = stats + l * 384;
    float* st2 = st1 + 256;
    if (l == 0) {
      k_agg0<<<NN / 4, 256, 0, stream>>>(h0, bemb, eps, l, row_ptr, epack, zA);
    } else {
      const float* stp = stats + (l - 1) * 384 + 256;
      k_aggbn<<<NN / 4, 256, 0, stream>>>(zB, bemb, eps, l, row_ptr, epack,
                                          stp, bng + (l - 1) * 64, bnb + (l - 1) * 64, zA);
    }
    k_gemm1<<<1024, 256, 0, stream>>>(zA, l1w, l1b, l, y, st1);
    k_gemm2<<<1024, 256, 0, stream>>>(y, l2w, l2b, g1, bb1, l, zB, st1, st2);
  }
  k_bn2<<<1024, 256, 0, stream>>>(zB, bng + 3 * 64, bnb + 3 * 64,
                                  stats + 3 * 384 + 256, out);
}